// Round 1
// baseline (2880.471 us; speedup 1.0000x reference)
//
#include <hip/hip_runtime.h>
#include <math.h>

#define C 128
#define PITCH 132   // LDS row pitch (floats): +4 pad keeps conflicts <= 2-way

// ---- degree count: deg[row[e]] += 1 (float atomics, exact to 2^24) ----
__global__ void deg_kernel(const int* __restrict__ rowI, float* __restrict__ deg, int E) {
    int e = blockIdx.x * blockDim.x + threadIdx.x;
    if (e < E) atomicAdd(&deg[rowI[e]], 1.0f);
}

// ---- in-place: deg -> rsqrt(deg + 1) ----
__global__ void inv_kernel(float* __restrict__ deg, int n) {
    int i = blockIdx.x * blockDim.x + threadIdx.x;
    if (i < n) deg[i] = rsqrtf(deg[i] + 1.0f);
}

// ---- self term: out[i][c] = x[i][c] * inv[i]  (float4, coalesced) ----
__global__ void init_kernel(const float4* __restrict__ x4, const float* __restrict__ inv,
                            float4* __restrict__ out4, int total4) {
    int i = blockIdx.x * blockDim.x + threadIdx.x;
    if (i >= total4) return;
    int node = i >> 5;               // 32 float4 per node (C=128)
    float s = inv[node];
    float4 v = x4[i];
    v.x *= s; v.y *= s; v.z *= s; v.w *= s;
    out4[i] = v;
}

// ---- edge scatter: out[row] += x[col] * inv[col]; 32 lanes per edge ----
__global__ void scatter_kernel(const float* __restrict__ x, const int* __restrict__ rowI,
                               const int* __restrict__ colI, const float* __restrict__ inv,
                               float* __restrict__ out, int E) {
    int t = blockIdx.x * blockDim.x + threadIdx.x;
    int e = t >> 5;
    if (e >= E) return;
    int q = t & 31;                  // float4 slot 0..31
    int r = rowI[e];
    int c = colI[e];
    float s = inv[c];
    const float4 v = *(const float4*)(x + (size_t)c * C + q * 4);
    float* dst = out + (size_t)r * C + q * 4;
    atomicAdd(dst + 0, v.x * s);
    atomicAdd(dst + 1, v.y * s);
    atomicAdd(dst + 2, v.z * s);
    atomicAdd(dst + 3, v.w * s);
}

// ---- final scale + GEMM: out[n] = (out[n] * inv[n]) @ W^T, in place ----
// Block: 512 threads, 128 nodes. LDS: Wt[k][o] and As[n][k], pitch 132.
// Thread tile: 4 nodes x 8 outputs (cols o0..o0+3 and o0+64..o0+67).
__global__ __launch_bounds__(512) void matmul_kernel(const float* __restrict__ W,
                                                     const float* __restrict__ inv,
                                                     float* __restrict__ out, int nodes) {
    __shared__ float Wt[128 * PITCH];   // Wt[k*PITCH + o] = W[o][k]
    __shared__ float As[128 * PITCH];   // As[n*PITCH + k] = out[base+n][k] * inv
    const int t = threadIdx.x;
    const int base = blockIdx.x * 128;

    // stage W transposed (coalesced global reads; LDS writes ~8-way, one-time)
    for (int i = t; i < 128 * 128; i += 512) {
        int o = i >> 7, k = i & 127;
        Wt[k * PITCH + o] = W[i];
    }
    // stage A rows, scaled (coalesced reads, conflict-free LDS writes)
    for (int i = t; i < 128 * 128; i += 512) {
        int n = i >> 7, k = i & 127;
        int node = base + n;
        float v = 0.0f;
        if (node < nodes) v = out[(size_t)node * C + k] * inv[node];
        As[n * PITCH + k] = v;
    }
    __syncthreads();

    const int og = t & 15;           // 16 output groups
    const int ng = t >> 4;           // 32 node groups
    const int o0 = og * 4;           // outputs o0..o0+3 and o0+64..o0+67
    const int n0 = ng * 4;

    float acc[4][8];
#pragma unroll
    for (int i = 0; i < 4; ++i)
#pragma unroll
        for (int j = 0; j < 8; ++j) acc[i][j] = 0.0f;

    for (int k = 0; k < 128; ++k) {
        float av[4];
#pragma unroll
        for (int i = 0; i < 4; ++i) av[i] = As[(n0 + i) * PITCH + k];
        const float4 w0 = *(const float4*)&Wt[k * PITCH + o0];
        const float4 w1 = *(const float4*)&Wt[k * PITCH + o0 + 64];
        const float wv[8] = {w0.x, w0.y, w0.z, w0.w, w1.x, w1.y, w1.z, w1.w};
#pragma unroll
        for (int i = 0; i < 4; ++i)
#pragma unroll
            for (int j = 0; j < 8; ++j)
                acc[i][j] = fmaf(av[i], wv[j], acc[i][j]);
    }

    // write back (reads of `out` all happened before the barrier)
#pragma unroll
    for (int i = 0; i < 4; ++i) {
        int node = base + n0 + i;
        if (node >= nodes) continue;
        float4 s0 = make_float4(acc[i][0], acc[i][1], acc[i][2], acc[i][3]);
        float4 s1 = make_float4(acc[i][4], acc[i][5], acc[i][6], acc[i][7]);
        *(float4*)(out + (size_t)node * C + o0) = s0;
        *(float4*)(out + (size_t)node * C + o0 + 64) = s1;
    }
}

extern "C" void kernel_launch(void* const* d_in, const int* in_sizes, int n_in,
                              void* d_out, int out_size, void* d_ws, size_t ws_size,
                              hipStream_t stream) {
    const float* x   = (const float*)d_in[0];
    const int*   ei  = (const int*)d_in[1];
    const float* W   = (const float*)d_in[2];
    float* out = (float*)d_out;

    const int N = in_sizes[0] / C;
    const int E = in_sizes[1] / 2;
    const int* rowI = ei;          // edge_index[0]
    const int* colI = ei + E;      // edge_index[1]

    float* deg = (float*)d_ws;     // N floats; becomes inv_sqrt in place

    hipMemsetAsync(deg, 0, (size_t)N * sizeof(float), stream);

    deg_kernel<<<(E + 255) / 256, 256, 0, stream>>>(rowI, deg, E);
    inv_kernel<<<(N + 255) / 256, 256, 0, stream>>>(deg, N);

    int total4 = N * (C / 4);
    init_kernel<<<(total4 + 255) / 256, 256, 0, stream>>>((const float4*)x, deg,
                                                          (float4*)out, total4);

    long long st = (long long)E * 32;
    scatter_kernel<<<(int)((st + 255) / 256), 256, 0, stream>>>(x, rowI, colI, deg, out, E);

    matmul_kernel<<<(N + 127) / 128, 512, 0, stream>>>(W, deg, out, N);
}

// Round 2
// 438.454 us; speedup vs baseline: 6.5696x; 6.5696x over previous
//
#include <hip/hip_runtime.h>
#include <math.h>

#define C 128
#define PITCH 132        // LDS row pitch (floats): +4 pad keeps conflicts <= 2-way
#define SCAN_CHUNK 2048  // elements per scan block (256 threads x 8)

// ---- degree count (int atomics) ----
__global__ void count_kernel(const int* __restrict__ rowI, int* __restrict__ deg, int E) {
    int e = blockIdx.x * blockDim.x + threadIdx.x;
    if (e < E) atomicAdd(&deg[rowI[e]], 1);
}

// ---- scan phase 1: per-block exclusive scan + block sums ----
__global__ __launch_bounds__(256) void scan1_kernel(const int* __restrict__ deg,
                                                    int* __restrict__ offs,
                                                    int* __restrict__ bsum, int N) {
    __shared__ int lds[256];
    int b = blockIdx.x, t = threadIdx.x;
    int base = b * SCAN_CHUNK + t * 8;
    int v[8];
    int sum = 0;
#pragma unroll
    for (int k = 0; k < 8; ++k) {
        int i = base + k;
        int d = (i < N) ? deg[i] : 0;
        v[k] = sum;              // exclusive within thread
        sum += d;
    }
    lds[t] = sum;
    __syncthreads();
    for (int o = 1; o < 256; o <<= 1) {   // Hillis-Steele inclusive scan
        int x = (t >= o) ? lds[t - o] : 0;
        __syncthreads();
        lds[t] += x;
        __syncthreads();
    }
    int excl = lds[t] - sum;     // exclusive prefix of thread sums
#pragma unroll
    for (int k = 0; k < 8; ++k) {
        int i = base + k;
        if (i < N) offs[i] = v[k] + excl;
    }
    if (t == 255) bsum[b] = lds[255];
}

// ---- scan phase 2: exclusive scan of block sums (small: ~49 entries) ----
__global__ void scan2_kernel(const int* __restrict__ bsum, int* __restrict__ boff, int nB) {
    if (threadIdx.x == 0 && blockIdx.x == 0) {
        int s = 0;
        for (int i = 0; i < nB; ++i) { boff[i] = s; s += bsum[i]; }
    }
}

// ---- scan phase 3: add block offsets; cursor copy; offs[N] = E ----
__global__ __launch_bounds__(256) void scan3_kernel(int* __restrict__ offs,
                                                    int* __restrict__ cursor,
                                                    const int* __restrict__ boff,
                                                    int N, int E) {
    int b = blockIdx.x, t = threadIdx.x;
    int add = boff[b];
    int base = b * SCAN_CHUNK + t * 8;
#pragma unroll
    for (int k = 0; k < 8; ++k) {
        int i = base + k;
        if (i < N) { int val = offs[i] + add; offs[i] = val; cursor[i] = val; }
    }
    if (b == gridDim.x - 1 && t == 255) offs[N] = E;
}

// ---- inv_sqrt(deg+1) ----
__global__ void inv_kernel(const int* __restrict__ deg, float* __restrict__ inv, int n) {
    int i = blockIdx.x * blockDim.x + threadIdx.x;
    if (i < n) inv[i] = rsqrtf((float)deg[i] + 1.0f);
}

// ---- CSR placement: csr[cursor[row[e]]++] = col[e] ----
__global__ void place_kernel(const int* __restrict__ rowI, const int* __restrict__ colI,
                             int* __restrict__ cursor, int* __restrict__ csr, int E) {
    int e = blockIdx.x * blockDim.x + threadIdx.x;
    if (e < E) {
        int r = rowI[e];
        int pos = atomicAdd(&cursor[r], 1);
        csr[pos] = colI[e];
    }
}

// ---- gather: 32 lanes per node; acc = x[n]*inv[n] + sum x[c]*inv[c]; one write ----
__global__ __launch_bounds__(256) void gather_kernel(const float4* __restrict__ x4,
                                                     const int* __restrict__ csr,
                                                     const int* __restrict__ offs,
                                                     const float* __restrict__ inv,
                                                     float4* __restrict__ out4, int N) {
    int t = blockIdx.x * blockDim.x + threadIdx.x;
    int node = t >> 5;
    if (node >= N) return;
    int lane = t & 31;
    int s = offs[node], e = offs[node + 1];
    float sn = inv[node];
    float4 a = x4[(size_t)node * 32 + lane];
    float4 acc = make_float4(a.x * sn, a.y * sn, a.z * sn, a.w * sn);
    for (int j = s; j < e; ++j) {
        int c = csr[j];                       // broadcast across 32 lanes
        float sc = inv[c];
        float4 v = x4[(size_t)c * 32 + lane]; // coalesced 512B row read (L3-resident)
        acc.x = fmaf(v.x, sc, acc.x);
        acc.y = fmaf(v.y, sc, acc.y);
        acc.z = fmaf(v.z, sc, acc.z);
        acc.w = fmaf(v.w, sc, acc.w);
    }
    out4[(size_t)node * 32 + lane] = acc;
}

// ---- final scale + GEMM: out[n] = (out[n] * inv[n]) @ W^T, in place ----
__global__ __launch_bounds__(512) void matmul_kernel(const float* __restrict__ W,
                                                     const float* __restrict__ inv,
                                                     float* __restrict__ out, int nodes) {
    __shared__ float Wt[128 * PITCH];   // Wt[k*PITCH + o] = W[o][k]
    __shared__ float As[128 * PITCH];   // As[n*PITCH + k] = out[base+n][k] * inv
    const int t = threadIdx.x;
    const int base = blockIdx.x * 128;

    for (int i = t; i < 128 * 128; i += 512) {
        int o = i >> 7, k = i & 127;
        Wt[k * PITCH + o] = W[i];
    }
    for (int i = t; i < 128 * 128; i += 512) {
        int n = i >> 7, k = i & 127;
        int node = base + n;
        float v = 0.0f;
        if (node < nodes) v = out[(size_t)node * C + k] * inv[node];
        As[n * PITCH + k] = v;
    }
    __syncthreads();

    const int og = t & 15;
    const int ng = t >> 4;
    const int o0 = og * 4;
    const int n0 = ng * 4;

    float acc[4][8];
#pragma unroll
    for (int i = 0; i < 4; ++i)
#pragma unroll
        for (int j = 0; j < 8; ++j) acc[i][j] = 0.0f;

    for (int k = 0; k < 128; ++k) {
        float av[4];
#pragma unroll
        for (int i = 0; i < 4; ++i) av[i] = As[(n0 + i) * PITCH + k];
        const float4 w0 = *(const float4*)&Wt[k * PITCH + o0];
        const float4 w1 = *(const float4*)&Wt[k * PITCH + o0 + 64];
        const float wv[8] = {w0.x, w0.y, w0.z, w0.w, w1.x, w1.y, w1.z, w1.w};
#pragma unroll
        for (int i = 0; i < 4; ++i)
#pragma unroll
            for (int j = 0; j < 8; ++j)
                acc[i][j] = fmaf(av[i], wv[j], acc[i][j]);
    }

#pragma unroll
    for (int i = 0; i < 4; ++i) {
        int node = base + n0 + i;
        if (node >= nodes) continue;
        float4 s0 = make_float4(acc[i][0], acc[i][1], acc[i][2], acc[i][3]);
        float4 s1 = make_float4(acc[i][4], acc[i][5], acc[i][6], acc[i][7]);
        *(float4*)(out + (size_t)node * C + o0) = s0;
        *(float4*)(out + (size_t)node * C + o0 + 64) = s1;
    }
}

extern "C" void kernel_launch(void* const* d_in, const int* in_sizes, int n_in,
                              void* d_out, int out_size, void* d_ws, size_t ws_size,
                              hipStream_t stream) {
    const float* x  = (const float*)d_in[0];
    const int*   ei = (const int*)d_in[1];
    const float* W  = (const float*)d_in[2];
    float* out = (float*)d_out;

    const int N = in_sizes[0] / C;
    const int E = in_sizes[1] / 2;
    const int* rowI = ei;        // edge_index[0]
    const int* colI = ei + E;    // edge_index[1]

    const int nB = (N + SCAN_CHUNK - 1) / SCAN_CHUNK;

    // workspace carve-up (256B-aligned regions)
    char* ws = (char*)d_ws;
    size_t off = 0;
    auto carve = [&](size_t bytes) -> void* {
        off = (off + 255) & ~(size_t)255;
        void* p = ws + off;
        off += bytes;
        return p;
    };
    int*   deg_i  = (int*)carve((size_t)N * 4);
    int*   offs   = (int*)carve((size_t)(N + 1) * 4);
    int*   cursor = (int*)carve((size_t)N * 4);
    float* inv    = (float*)carve((size_t)N * 4);
    int*   bsum   = (int*)carve((size_t)nB * 4);
    int*   boff   = (int*)carve((size_t)nB * 4);
    int*   csr    = (int*)carve((size_t)E * 4);

    hipMemsetAsync(deg_i, 0, (size_t)N * 4, stream);

    count_kernel<<<(E + 255) / 256, 256, 0, stream>>>(rowI, deg_i, E);
    scan1_kernel<<<nB, 256, 0, stream>>>(deg_i, offs, bsum, N);
    scan2_kernel<<<1, 64, 0, stream>>>(bsum, boff, nB);
    scan3_kernel<<<nB, 256, 0, stream>>>(offs, cursor, boff, N, E);
    inv_kernel<<<(N + 255) / 256, 256, 0, stream>>>(deg_i, inv, N);
    place_kernel<<<(E + 255) / 256, 256, 0, stream>>>(rowI, colI, cursor, csr, E);

    long long gt = (long long)N * 32;
    gather_kernel<<<(int)((gt + 255) / 256), 256, 0, stream>>>((const float4*)x, csr, offs,
                                                               inv, (float4*)out, N);
    matmul_kernel<<<(N + 127) / 128, 512, 0, stream>>>(W, inv, out, N);
}

// Round 3
// 386.795 us; speedup vs baseline: 7.4470x; 1.1336x over previous
//
#include <hip/hip_runtime.h>
#include <hip/hip_fp16.h>
#include <math.h>

#define C 128
#define PITCH 132        // LDS row pitch (floats): +4 pad keeps conflicts <= 2-way
#define SCAN_CHUNK 2048  // elements per scan block (256 threads x 8)

// ---- degree count, 4 edges/thread (int4) ----
__global__ void count4_kernel(const int4* __restrict__ rowI4, const int* __restrict__ rowI,
                              int* __restrict__ deg, int E) {
    int i = blockIdx.x * blockDim.x + threadIdx.x;
    int base = i * 4;
    if (base >= E) return;
    if (base + 4 <= E) {
        int4 r = rowI4[i];
        atomicAdd(&deg[r.x], 1);
        atomicAdd(&deg[r.y], 1);
        atomicAdd(&deg[r.z], 1);
        atomicAdd(&deg[r.w], 1);
    } else {
        for (int k = base; k < E; ++k) atomicAdd(&deg[rowI[k]], 1);
    }
}

// ---- scan phase 1: per-block exclusive scan of deg + block sums ----
__global__ __launch_bounds__(256) void scan1_kernel(const int* __restrict__ deg,
                                                    int* __restrict__ offs,
                                                    int* __restrict__ bsum, int N) {
    __shared__ int lds[256];
    int b = blockIdx.x, t = threadIdx.x;
    int base = b * SCAN_CHUNK + t * 8;
    int v[8];
    int sum = 0;
#pragma unroll
    for (int k = 0; k < 8; ++k) {
        int i = base + k;
        int d = (i < N) ? deg[i] : 0;
        v[k] = sum;
        sum += d;
    }
    lds[t] = sum;
    __syncthreads();
    for (int o = 1; o < 256; o <<= 1) {
        int x = (t >= o) ? lds[t - o] : 0;
        __syncthreads();
        lds[t] += x;
        __syncthreads();
    }
    int excl = lds[t] - sum;
#pragma unroll
    for (int k = 0; k < 8; ++k) {
        int i = base + k;
        if (i < N) offs[i] = v[k] + excl;
    }
    if (t == 255) bsum[b] = lds[255];
}

// ---- scan phase 2+3 fused: add prefix of block sums (nB ~ 49, serial ok) ----
__global__ __launch_bounds__(256) void scan3_kernel(int* __restrict__ offs,
                                                    const int* __restrict__ bsum, int N) {
    __shared__ int addS;
    int b = blockIdx.x, t = threadIdx.x;
    if (t == 0) {
        int s = 0;
        for (int i = 0; i < b; ++i) s += bsum[i];
        addS = s;
    }
    __syncthreads();
    int add = addS;
    int base = b * SCAN_CHUNK + t * 8;
#pragma unroll
    for (int k = 0; k < 8; ++k) {
        int i = base + k;
        if (i < N) offs[i] += add;
    }
}

// ---- prescale: xsh[n][c] = fp16(x[n][c] * rsqrt(deg[n]+1)); thread = 4 channels ----
__global__ __launch_bounds__(256) void prescale_kernel(const float4* __restrict__ x4,
                                                       const int* __restrict__ deg,
                                                       __half2* __restrict__ xsh2, int total4) {
    int i = blockIdx.x * blockDim.x + threadIdx.x;
    if (i >= total4) return;
    int node = i >> 5;                    // 32 float4 per row
    float s = rsqrtf((float)deg[node] + 1.0f);
    float4 v = x4[i];
    xsh2[i * 2]     = __floats2half2_rn(v.x * s, v.y * s);
    xsh2[i * 2 + 1] = __floats2half2_rn(v.z * s, v.w * s);
}

// ---- CSR placement: offs doubles as cursor (post: offs[i] = segment end) ----
__global__ void place4_kernel(const int4* __restrict__ rowI4, const int4* __restrict__ colI4,
                              const int* __restrict__ rowI, const int* __restrict__ colI,
                              int* __restrict__ offs, int* __restrict__ csr, int E) {
    int i = blockIdx.x * blockDim.x + threadIdx.x;
    int base = i * 4;
    if (base >= E) return;
    if (base + 4 <= E) {
        int4 r = rowI4[i];
        int4 c = colI4[i];
        int p0 = atomicAdd(&offs[r.x], 1);
        int p1 = atomicAdd(&offs[r.y], 1);
        int p2 = atomicAdd(&offs[r.z], 1);
        int p3 = atomicAdd(&offs[r.w], 1);
        csr[p0] = c.x;
        csr[p1] = c.y;
        csr[p2] = c.z;
        csr[p3] = c.w;
    } else {
        for (int k = base; k < E; ++k) {
            int pos = atomicAdd(&offs[rowI[k]], 1);
            csr[pos] = colI[k];
        }
    }
}

// ---- gather: 16 lanes per node, fp16 rows (256B), fp32 accumulate, unroll 2 ----
__global__ __launch_bounds__(256) void gather_kernel(const float4* __restrict__ xsh4,
                                                     const int* __restrict__ offs_end,
                                                     const int* __restrict__ csr,
                                                     float4* __restrict__ out4, int N) {
    int t = blockIdx.x * blockDim.x + threadIdx.x;
    int node = t >> 4;
    if (node >= N) return;
    int lane = t & 15;
    int s = (node == 0) ? 0 : offs_end[node - 1];
    int e = offs_end[node];

    float a[8];
    {   // self term (already inv-scaled in xsh)
        float4 h = xsh4[(size_t)node * 16 + lane];
        const __half2* p = (const __half2*)&h;
#pragma unroll
        for (int q = 0; q < 4; ++q) {
            float2 f = __half22float2(p[q]);
            a[2 * q] = f.x; a[2 * q + 1] = f.y;
        }
    }
    int j = s;
    for (; j + 2 <= e; j += 2) {
        int c0 = csr[j], c1 = csr[j + 1];
        float4 v0 = xsh4[(size_t)c0 * 16 + lane];
        float4 v1 = xsh4[(size_t)c1 * 16 + lane];
        const __half2* p0 = (const __half2*)&v0;
        const __half2* p1 = (const __half2*)&v1;
#pragma unroll
        for (int q = 0; q < 4; ++q) {
            float2 f = __half22float2(p0[q]);
            a[2 * q] += f.x; a[2 * q + 1] += f.y;
        }
#pragma unroll
        for (int q = 0; q < 4; ++q) {
            float2 f = __half22float2(p1[q]);
            a[2 * q] += f.x; a[2 * q + 1] += f.y;
        }
    }
    if (j < e) {
        int c = csr[j];
        float4 v = xsh4[(size_t)c * 16 + lane];
        const __half2* p = (const __half2*)&v;
#pragma unroll
        for (int q = 0; q < 4; ++q) {
            float2 f = __half22float2(p[q]);
            a[2 * q] += f.x; a[2 * q + 1] += f.y;
        }
    }
    size_t ob = (size_t)node * 32 + lane * 2;
    out4[ob]     = make_float4(a[0], a[1], a[2], a[3]);
    out4[ob + 1] = make_float4(a[4], a[5], a[6], a[7]);
}

// ---- final scale + GEMM: out[n] = (out[n] * rsqrt(deg[n]+1)) @ W^T, in place ----
__global__ __launch_bounds__(512) void matmul_kernel(const float* __restrict__ W,
                                                     const int* __restrict__ deg,
                                                     float* __restrict__ out, int nodes) {
    __shared__ float Wt[128 * PITCH];   // Wt[k*PITCH + o] = W[o][k]
    __shared__ float As[128 * PITCH];   // As[n*PITCH + k] = out[base+n][k] * inv
    const int t = threadIdx.x;
    const int base = blockIdx.x * 128;

    for (int i = t; i < 128 * 128; i += 512) {
        int o = i >> 7, k = i & 127;
        Wt[k * PITCH + o] = W[i];
    }
    for (int i = t; i < 128 * 128; i += 512) {
        int n = i >> 7, k = i & 127;
        int node = base + n;
        float v = 0.0f;
        if (node < nodes) v = out[(size_t)node * C + k] * rsqrtf((float)deg[node] + 1.0f);
        As[n * PITCH + k] = v;
    }
    __syncthreads();

    const int og = t & 15;
    const int ng = t >> 4;
    const int o0 = og * 4;
    const int n0 = ng * 4;

    float acc[4][8];
#pragma unroll
    for (int i = 0; i < 4; ++i)
#pragma unroll
        for (int j = 0; j < 8; ++j) acc[i][j] = 0.0f;

    for (int k = 0; k < 128; ++k) {
        float av[4];
#pragma unroll
        for (int i = 0; i < 4; ++i) av[i] = As[(n0 + i) * PITCH + k];
        const float4 w0 = *(const float4*)&Wt[k * PITCH + o0];
        const float4 w1 = *(const float4*)&Wt[k * PITCH + o0 + 64];
        const float wv[8] = {w0.x, w0.y, w0.z, w0.w, w1.x, w1.y, w1.z, w1.w};
#pragma unroll
        for (int i = 0; i < 4; ++i)
#pragma unroll
            for (int j = 0; j < 8; ++j)
                acc[i][j] = fmaf(av[i], wv[j], acc[i][j]);
    }

#pragma unroll
    for (int i = 0; i < 4; ++i) {
        int node = base + n0 + i;
        if (node >= nodes) continue;
        float4 s0 = make_float4(acc[i][0], acc[i][1], acc[i][2], acc[i][3]);
        float4 s1 = make_float4(acc[i][4], acc[i][5], acc[i][6], acc[i][7]);
        *(float4*)(out + (size_t)node * C + o0) = s0;
        *(float4*)(out + (size_t)node * C + o0 + 64) = s1;
    }
}

extern "C" void kernel_launch(void* const* d_in, const int* in_sizes, int n_in,
                              void* d_out, int out_size, void* d_ws, size_t ws_size,
                              hipStream_t stream) {
    const float* x  = (const float*)d_in[0];
    const int*   ei = (const int*)d_in[1];
    const float* W  = (const float*)d_in[2];
    float* out = (float*)d_out;

    const int N = in_sizes[0] / C;
    const int E = in_sizes[1] / 2;
    const int* rowI = ei;        // edge_index[0]
    const int* colI = ei + E;    // edge_index[1]

    const int nB = (N + SCAN_CHUNK - 1) / SCAN_CHUNK;

    // workspace carve-up (256B-aligned regions)
    char* ws = (char*)d_ws;
    size_t off = 0;
    auto carve = [&](size_t bytes) -> void* {
        off = (off + 255) & ~(size_t)255;
        void* p = ws + off;
        off += bytes;
        return p;
    };
    int*     deg_i = (int*)carve((size_t)N * 4);
    int*     offs  = (int*)carve((size_t)N * 4);
    int*     bsum  = (int*)carve((size_t)nB * 4);
    int*     csr   = (int*)carve((size_t)E * 4);
    __half2* xsh   = (__half2*)carve((size_t)N * C * 2);   // fp16 prescaled features

    hipMemsetAsync(deg_i, 0, (size_t)N * 4, stream);

    int e4 = (E + 3) / 4;
    count4_kernel<<<(e4 + 255) / 256, 256, 0, stream>>>((const int4*)rowI, rowI, deg_i, E);
    scan1_kernel<<<nB, 256, 0, stream>>>(deg_i, offs, bsum, N);
    scan3_kernel<<<nB, 256, 0, stream>>>(offs, bsum, N);

    int total4 = N * (C / 4);
    prescale_kernel<<<(total4 + 255) / 256, 256, 0, stream>>>((const float4*)x, deg_i, xsh,
                                                              total4);

    place4_kernel<<<(e4 + 255) / 256, 256, 0, stream>>>((const int4*)rowI, (const int4*)colI,
                                                        rowI, colI, offs, csr, E);

    long long gt = (long long)N * 16;
    gather_kernel<<<(int)((gt + 255) / 256), 256, 0, stream>>>((const float4*)xsh, offs, csr,
                                                               (float4*)out, N);
    matmul_kernel<<<(N + 127) / 128, 512, 0, stream>>>(W, deg_i, out, N);
}

// Round 4
// 238.457 us; speedup vs baseline: 12.0796x; 1.6221x over previous
//
#include <hip/hip_runtime.h>
#include <hip/hip_fp16.h>
#include <math.h>

#define C 128
#define PITCH 132       // LDS row pitch (floats) for matmul: +4 pad, <=2-way conflicts
#define BSHIFT 9        // bucket width = 512 nodes
#define BWIDTH 512
#define NBMAX 256       // >= ceil(100000/512)=196

// ---- 1. bucket histogram: bcount[row>>9] += 1 (LDS-aggregated) ----
__global__ __launch_bounds__(256) void bucket_hist_kernel(const int4* __restrict__ rowI4,
                                                          const int* __restrict__ rowI,
                                                          int* __restrict__ bcount,
                                                          int E4, int E, int NB) {
    __shared__ int h[NBMAX];
    int t = threadIdx.x;
    h[t] = 0;
    __syncthreads();
    for (int i = blockIdx.x * 256 + t; i < E4; i += gridDim.x * 256) {
        int4 r = rowI4[i];
        atomicAdd(&h[r.x >> BSHIFT], 1);
        atomicAdd(&h[r.y >> BSHIFT], 1);
        atomicAdd(&h[r.z >> BSHIFT], 1);
        atomicAdd(&h[r.w >> BSHIFT], 1);
    }
    if (blockIdx.x == 0 && t == 0) {          // tail (E not multiple of 4)
        for (int e = E4 * 4; e < E; ++e) atomicAdd(&h[rowI[e] >> BSHIFT], 1);
    }
    __syncthreads();
    if (t < NB && h[t]) atomicAdd(&bcount[t], h[t]);
}

// ---- 2. bucket scan: bstart[0..NB] exclusive prefix; gcur init ----
__global__ void bucket_scan_kernel(const int* __restrict__ bcount, int* __restrict__ bstart,
                                   int* __restrict__ gcur, int NB) {
    if (blockIdx.x == 0 && threadIdx.x == 0) {
        int s = 0;
        for (int i = 0; i < NB; ++i) {
            bstart[i] = s;
            gcur[i] = s;
            s += bcount[i];
        }
        bstart[NB] = s;
    }
}

// ---- 3. scatter edges into bucket-ordered ebuf (packed int2 {row,col}) ----
__global__ __launch_bounds__(256) void p2_scatter_kernel(const int* __restrict__ rowI,
                                                         const int* __restrict__ colI,
                                                         int* __restrict__ gcur,
                                                         int2* __restrict__ ebuf, int E) {
    __shared__ int cnt[NBMAX];
    __shared__ int base[NBMAX];
    const int t = threadIdx.x;
    cnt[t] = 0;
    __syncthreads();
    const int chunk = blockIdx.x * 4096;
    int ranks[16];
#pragma unroll
    for (int k = 0; k < 16; ++k) {
        int e = chunk + k * 256 + t;
        if (e < E) {
            int r = rowI[e];
            ranks[k] = atomicAdd(&cnt[r >> BSHIFT], 1);
        }
    }
    __syncthreads();
    {
        int c = cnt[t];
        base[t] = c ? atomicAdd(&gcur[t], c) : 0;
    }
    __syncthreads();
#pragma unroll
    for (int k = 0; k < 16; ++k) {
        int e = chunk + k * 256 + t;
        if (e < E) {
            int r = rowI[e];           // L1/L2 hot re-read
            int c = colI[e];
            ebuf[base[r >> BSHIFT] + ranks[k]] = make_int2(r, c);
        }
    }
}

// ---- 4. per-bucket place: LDS count + scan + LDS-cursor placement ----
// Also emits offs_end[node] (global inclusive end) and inv[node] = rsqrt(deg+1).
__global__ __launch_bounds__(512) void p3_place_kernel(const int2* __restrict__ ebuf,
                                                       const int* __restrict__ bstart,
                                                       int* __restrict__ offs_end,
                                                       float* __restrict__ inv,
                                                       int* __restrict__ csr, int N) {
    __shared__ int cnt[BWIDTH];
    __shared__ int sc[BWIDTH];
    const int b = blockIdx.x;
    const int t = threadIdx.x;
    const int rowBase = b << BSHIFT;
    const int eS = bstart[b];
    const int eE = bstart[b + 1];

    cnt[t] = 0;
    __syncthreads();
    for (int j = eS + t; j < eE; j += 512) {
        int2 rc = ebuf[j];
        atomicAdd(&cnt[rc.x - rowBase], 1);
    }
    __syncthreads();
    sc[t] = cnt[t];
    __syncthreads();
    for (int o = 1; o < 512; o <<= 1) {       // Hillis-Steele inclusive scan
        int v = (t >= o) ? sc[t - o] : 0;
        __syncthreads();
        sc[t] += v;
        __syncthreads();
    }
    int node = rowBase + t;
    int myCnt = cnt[t];
    if (node < N) {
        offs_end[node] = eS + sc[t];
        inv[node] = rsqrtf((float)myCnt + 1.0f);
    }
    __syncthreads();
    cnt[t] = eS + sc[t] - myCnt;              // exclusive start -> cursor
    __syncthreads();
    for (int j = eS + t; j < eE; j += 512) {
        int2 rc = ebuf[j];
        int pos = atomicAdd(&cnt[rc.x - rowBase], 1);
        csr[pos] = rc.y;
    }
}

// ---- 5. prescale: xsh[n][c] = fp16(x[n][c] * inv[n]) ----
__global__ __launch_bounds__(256) void prescale_kernel(const float4* __restrict__ x4,
                                                       const float* __restrict__ inv,
                                                       __half2* __restrict__ xsh2, int total4) {
    int i = blockIdx.x * blockDim.x + threadIdx.x;
    if (i >= total4) return;
    int node = i >> 5;                    // 32 float4 per row
    float s = inv[node];
    float4 v = x4[i];
    xsh2[i * 2]     = __floats2half2_rn(v.x * s, v.y * s);
    xsh2[i * 2 + 1] = __floats2half2_rn(v.z * s, v.w * s);
}

// ---- 6. gather: 16 lanes per node, fp16 rows (256B), fp32 accumulate ----
__global__ __launch_bounds__(256) void gather_kernel(const float4* __restrict__ xsh4,
                                                     const int* __restrict__ offs_end,
                                                     const int* __restrict__ csr,
                                                     float4* __restrict__ out4, int N) {
    int t = blockIdx.x * blockDim.x + threadIdx.x;
    int node = t >> 4;
    if (node >= N) return;
    int lane = t & 15;
    int s = (node == 0) ? 0 : offs_end[node - 1];
    int e = offs_end[node];

    float a[8];
    {   // self term (already inv-scaled in xsh)
        float4 h = xsh4[(size_t)node * 16 + lane];
        const __half2* p = (const __half2*)&h;
#pragma unroll
        for (int q = 0; q < 4; ++q) {
            float2 f = __half22float2(p[q]);
            a[2 * q] = f.x; a[2 * q + 1] = f.y;
        }
    }
    int j = s;
    for (; j + 2 <= e; j += 2) {
        int c0 = csr[j], c1 = csr[j + 1];
        float4 v0 = xsh4[(size_t)c0 * 16 + lane];
        float4 v1 = xsh4[(size_t)c1 * 16 + lane];
        const __half2* p0 = (const __half2*)&v0;
        const __half2* p1 = (const __half2*)&v1;
#pragma unroll
        for (int q = 0; q < 4; ++q) {
            float2 f = __half22float2(p0[q]);
            a[2 * q] += f.x; a[2 * q + 1] += f.y;
        }
#pragma unroll
        for (int q = 0; q < 4; ++q) {
            float2 f = __half22float2(p1[q]);
            a[2 * q] += f.x; a[2 * q + 1] += f.y;
        }
    }
    if (j < e) {
        int c = csr[j];
        float4 v = xsh4[(size_t)c * 16 + lane];
        const __half2* p = (const __half2*)&v;
#pragma unroll
        for (int q = 0; q < 4; ++q) {
            float2 f = __half22float2(p[q]);
            a[2 * q] += f.x; a[2 * q + 1] += f.y;
        }
    }
    size_t ob = (size_t)node * 32 + lane * 2;
    out4[ob]     = make_float4(a[0], a[1], a[2], a[3]);
    out4[ob + 1] = make_float4(a[4], a[5], a[6], a[7]);
}

// ---- 7. final scale + GEMM: out[n] = (out[n] * inv[n]) @ W^T, in place ----
__global__ __launch_bounds__(512) void matmul_kernel(const float* __restrict__ W,
                                                     const float* __restrict__ inv,
                                                     float* __restrict__ out, int nodes) {
    __shared__ float Wt[128 * PITCH];
    __shared__ float As[128 * PITCH];
    const int t = threadIdx.x;
    const int base = blockIdx.x * 128;

    for (int i = t; i < 128 * 128; i += 512) {
        int o = i >> 7, k = i & 127;
        Wt[k * PITCH + o] = W[i];
    }
    for (int i = t; i < 128 * 128; i += 512) {
        int n = i >> 7, k = i & 127;
        int node = base + n;
        float v = 0.0f;
        if (node < nodes) v = out[(size_t)node * C + k] * inv[node];
        As[n * PITCH + k] = v;
    }
    __syncthreads();

    const int og = t & 15;
    const int ng = t >> 4;
    const int o0 = og * 4;
    const int n0 = ng * 4;

    float acc[4][8];
#pragma unroll
    for (int i = 0; i < 4; ++i)
#pragma unroll
        for (int j = 0; j < 8; ++j) acc[i][j] = 0.0f;

    for (int k = 0; k < 128; ++k) {
        float av[4];
#pragma unroll
        for (int i = 0; i < 4; ++i) av[i] = As[(n0 + i) * PITCH + k];
        const float4 w0 = *(const float4*)&Wt[k * PITCH + o0];
        const float4 w1 = *(const float4*)&Wt[k * PITCH + o0 + 64];
        const float wv[8] = {w0.x, w0.y, w0.z, w0.w, w1.x, w1.y, w1.z, w1.w};
#pragma unroll
        for (int i = 0; i < 4; ++i)
#pragma unroll
            for (int j = 0; j < 8; ++j)
                acc[i][j] = fmaf(av[i], wv[j], acc[i][j]);
    }

#pragma unroll
    for (int i = 0; i < 4; ++i) {
        int node = base + n0 + i;
        if (node >= nodes) continue;
        float4 s0 = make_float4(acc[i][0], acc[i][1], acc[i][2], acc[i][3]);
        float4 s1 = make_float4(acc[i][4], acc[i][5], acc[i][6], acc[i][7]);
        *(float4*)(out + (size_t)node * C + o0) = s0;
        *(float4*)(out + (size_t)node * C + o0 + 64) = s1;
    }
}

extern "C" void kernel_launch(void* const* d_in, const int* in_sizes, int n_in,
                              void* d_out, int out_size, void* d_ws, size_t ws_size,
                              hipStream_t stream) {
    const float* x  = (const float*)d_in[0];
    const int*   ei = (const int*)d_in[1];
    const float* W  = (const float*)d_in[2];
    float* out = (float*)d_out;

    const int N = in_sizes[0] / C;
    const int E = in_sizes[1] / 2;
    const int* rowI = ei;        // edge_index[0]
    const int* colI = ei + E;    // edge_index[1]

    const int NB = (N + BWIDTH - 1) / BWIDTH;     // 196 for N=100000

    // workspace carve-up (256B-aligned regions)
    char* ws = (char*)d_ws;
    size_t off = 0;
    auto carve = [&](size_t bytes) -> void* {
        off = (off + 255) & ~(size_t)255;
        void* p = ws + off;
        off += bytes;
        return p;
    };
    int*     bcount   = (int*)carve((size_t)NBMAX * 4);
    int*     bstart   = (int*)carve((size_t)(NBMAX + 1) * 4);
    int*     gcur     = (int*)carve((size_t)NBMAX * 4);
    int*     offs_end = (int*)carve((size_t)N * 4);
    float*   inv      = (float*)carve((size_t)N * 4);
    int*     csr      = (int*)carve((size_t)E * 4);
    int2*    ebuf     = (int2*)carve((size_t)E * 8);
    __half2* xsh      = (__half2*)carve((size_t)N * C * 2);

    hipMemsetAsync(bcount, 0, (size_t)NBMAX * 4, stream);

    int E4 = E >> 2;
    bucket_hist_kernel<<<256, 256, 0, stream>>>((const int4*)rowI, rowI, bcount, E4, E, NB);
    bucket_scan_kernel<<<1, 64, 0, stream>>>(bcount, bstart, gcur, NB);

    int nChunks = (E + 4095) / 4096;
    p2_scatter_kernel<<<nChunks, 256, 0, stream>>>(rowI, colI, gcur, ebuf, E);
    p3_place_kernel<<<NB, 512, 0, stream>>>(ebuf, bstart, offs_end, inv, csr, N);

    int total4 = N * (C / 4);
    prescale_kernel<<<(total4 + 255) / 256, 256, 0, stream>>>((const float4*)x, inv, xsh,
                                                              total4);

    long long gt = (long long)N * 16;
    gather_kernel<<<(int)((gt + 255) / 256), 256, 0, stream>>>((const float4*)xsh, offs_end,
                                                               csr, (float4*)out, N);
    matmul_kernel<<<(N + 127) / 128, 512, 0, stream>>>(W, inv, out, N);
}

// Round 5
// 176.102 us; speedup vs baseline: 16.3568x; 1.3541x over previous
//
#include <hip/hip_runtime.h>
#include <hip/hip_fp16.h>
#include <math.h>

#define C 128
#define BSHIFT 9        // bucket width = 512 nodes
#define BWIDTH 512
#define NBMAX 256       // >= ceil(100000/512)=196
#define COLBITS 17      // N=100000 < 2^17; ebuf packs (lrow<<17)|col

typedef _Float16 v8hf __attribute__((ext_vector_type(8)));
typedef float v4f __attribute__((ext_vector_type(4)));

// ---- 1. bucket histogram: bcount[row>>9] += 1 (LDS-aggregated) ----
__global__ __launch_bounds__(256) void bucket_hist_kernel(const int4* __restrict__ rowI4,
                                                          const int* __restrict__ rowI,
                                                          int* __restrict__ bcount,
                                                          int E4, int E, int NB) {
    __shared__ int h[NBMAX];
    int t = threadIdx.x;
    h[t] = 0;
    __syncthreads();
    for (int i = blockIdx.x * 256 + t; i < E4; i += gridDim.x * 256) {
        int4 r = rowI4[i];
        atomicAdd(&h[r.x >> BSHIFT], 1);
        atomicAdd(&h[r.y >> BSHIFT], 1);
        atomicAdd(&h[r.z >> BSHIFT], 1);
        atomicAdd(&h[r.w >> BSHIFT], 1);
    }
    if (blockIdx.x == 0 && t == 0) {          // tail (E not multiple of 4)
        for (int e = E4 * 4; e < E; ++e) atomicAdd(&h[rowI[e] >> BSHIFT], 1);
    }
    __syncthreads();
    if (t < NB && h[t]) atomicAdd(&bcount[t], h[t]);
}

// ---- 2. bucket scan: bstart[0..NB] exclusive prefix; gcur init ----
__global__ void bucket_scan_kernel(const int* __restrict__ bcount, int* __restrict__ bstart,
                                   int* __restrict__ gcur, int NB) {
    if (blockIdx.x == 0 && threadIdx.x == 0) {
        int s = 0;
        for (int i = 0; i < NB; ++i) {
            bstart[i] = s;
            gcur[i] = s;
            s += bcount[i];
        }
        bstart[NB] = s;
    }
}

// ---- 3. scatter edges into bucket-ordered ebuf, packed (lrow<<17)|col ----
__global__ __launch_bounds__(256) void p2_scatter_kernel(const int* __restrict__ rowI,
                                                         const int* __restrict__ colI,
                                                         int* __restrict__ gcur,
                                                         unsigned* __restrict__ ebuf, int E) {
    __shared__ int cnt[NBMAX];
    __shared__ int base[NBMAX];
    const int t = threadIdx.x;
    cnt[t] = 0;
    __syncthreads();
    const int chunk = blockIdx.x * 4096;
    int ranks[16];
#pragma unroll
    for (int k = 0; k < 16; ++k) {
        int e = chunk + k * 256 + t;
        if (e < E) {
            int r = rowI[e];
            ranks[k] = atomicAdd(&cnt[r >> BSHIFT], 1);
        }
    }
    __syncthreads();
    {
        int c = cnt[t];
        base[t] = c ? atomicAdd(&gcur[t], c) : 0;
    }
    __syncthreads();
#pragma unroll
    for (int k = 0; k < 16; ++k) {
        int e = chunk + k * 256 + t;
        if (e < E) {
            int r = rowI[e];           // L1-hot re-read
            unsigned c = (unsigned)colI[e];
            unsigned packed = ((unsigned)(r & (BWIDTH - 1)) << COLBITS) | c;
            ebuf[base[r >> BSHIFT] + ranks[k]] = packed;
        }
    }
}

// ---- 4. per-bucket place: LDS count + scan + LDS-cursor placement ----
// Emits offs_end[node], inv[node] = rsqrt(deg+1), csr (cols only).
__global__ __launch_bounds__(512) void p3_place_kernel(const unsigned* __restrict__ ebuf,
                                                       const int* __restrict__ bstart,
                                                       int* __restrict__ offs_end,
                                                       float* __restrict__ inv,
                                                       int* __restrict__ csr, int N) {
    __shared__ int cnt[BWIDTH];
    __shared__ int sc[BWIDTH];
    const int b = blockIdx.x;
    const int t = threadIdx.x;
    const int rowBase = b << BSHIFT;
    const int eS = bstart[b];
    const int eE = bstart[b + 1];

    cnt[t] = 0;
    __syncthreads();
    for (int j = eS + t; j < eE; j += 512) {
        unsigned rc = ebuf[j];
        atomicAdd(&cnt[rc >> COLBITS], 1);
    }
    __syncthreads();
    sc[t] = cnt[t];
    __syncthreads();
    for (int o = 1; o < 512; o <<= 1) {       // Hillis-Steele inclusive scan
        int v = (t >= o) ? sc[t - o] : 0;
        __syncthreads();
        sc[t] += v;
        __syncthreads();
    }
    int node = rowBase + t;
    int myCnt = cnt[t];
    if (node < N) {
        offs_end[node] = eS + sc[t];
        inv[node] = rsqrtf((float)myCnt + 1.0f);
    }
    __syncthreads();
    cnt[t] = eS + sc[t] - myCnt;              // exclusive start -> cursor
    __syncthreads();
    for (int j = eS + t; j < eE; j += 512) {
        unsigned rc = ebuf[j];
        int pos = atomicAdd(&cnt[rc >> COLBITS], 1);
        csr[pos] = (int)(rc & ((1u << COLBITS) - 1));
    }
}

// ---- 5. prescale: xsh[n][c] = fp16(x[n][c] * inv[n]) ----
__global__ __launch_bounds__(256) void prescale_kernel(const float4* __restrict__ x4,
                                                       const float* __restrict__ inv,
                                                       __half2* __restrict__ xsh2, int total4) {
    int i = blockIdx.x * blockDim.x + threadIdx.x;
    if (i >= total4) return;
    int node = i >> 5;                    // 32 float4 per row
    float s = inv[node];
    float4 v = x4[i];
    xsh2[i * 2]     = __floats2half2_rn(v.x * s, v.y * s);
    xsh2[i * 2 + 1] = __floats2half2_rn(v.z * s, v.w * s);
}

// ---- 6. gather: 16 lanes/node; fp32 accumulate; write fp16 agg*inv[dest] ----
__global__ __launch_bounds__(256) void gather_kernel(const float4* __restrict__ xsh4,
                                                     const int* __restrict__ offs_end,
                                                     const int* __restrict__ csr,
                                                     const float* __restrict__ inv,
                                                     float4* __restrict__ aggh4, int N) {
    int t = blockIdx.x * blockDim.x + threadIdx.x;
    int node = t >> 4;
    if (node >= N) return;
    int lane = t & 15;
    int s = (node == 0) ? 0 : offs_end[node - 1];
    int e = offs_end[node];

    float a[8];
    {   // self term (already inv-scaled in xsh)
        float4 h = xsh4[(size_t)node * 16 + lane];
        const __half2* p = (const __half2*)&h;
#pragma unroll
        for (int q = 0; q < 4; ++q) {
            float2 f = __half22float2(p[q]);
            a[2 * q] = f.x; a[2 * q + 1] = f.y;
        }
    }
    int j = s;
    for (; j + 2 <= e; j += 2) {
        int c0 = csr[j], c1 = csr[j + 1];
        float4 v0 = xsh4[(size_t)c0 * 16 + lane];
        float4 v1 = xsh4[(size_t)c1 * 16 + lane];
        const __half2* p0 = (const __half2*)&v0;
        const __half2* p1 = (const __half2*)&v1;
#pragma unroll
        for (int q = 0; q < 4; ++q) {
            float2 f = __half22float2(p0[q]);
            a[2 * q] += f.x; a[2 * q + 1] += f.y;
        }
#pragma unroll
        for (int q = 0; q < 4; ++q) {
            float2 f = __half22float2(p1[q]);
            a[2 * q] += f.x; a[2 * q + 1] += f.y;
        }
    }
    if (j < e) {
        int c = csr[j];
        float4 v = xsh4[(size_t)c * 16 + lane];
        const __half2* p = (const __half2*)&v;
#pragma unroll
        for (int q = 0; q < 4; ++q) {
            float2 f = __half22float2(p[q]);
            a[2 * q] += f.x; a[2 * q + 1] += f.y;
        }
    }
    float invn = inv[node];
    __half2 h[4];
#pragma unroll
    for (int q = 0; q < 4; ++q)
        h[q] = __floats2half2_rn(a[2 * q] * invn, a[2 * q + 1] * invn);
    aggh4[(size_t)node * 16 + lane] = *(const float4*)h;
}

// ---- 7. W -> fp16 ----
__global__ void wconv_kernel(const float4* __restrict__ W4, __half2* __restrict__ Wh2,
                             int total4) {
    int i = blockIdx.x * blockDim.x + threadIdx.x;
    if (i >= total4) return;
    float4 v = W4[i];
    Wh2[i * 2]     = __floats2half2_rn(v.x, v.y);
    Wh2[i * 2 + 1] = __floats2half2_rn(v.z, v.w);
}

// ---- 8. MFMA GEMM: out[n][o] = sum_k A[n][k] * Wh[o][k]  (A,Wh fp16, out fp32)
// Block = 256 threads = 4 waves; wave owns 16 rows x 128 cols; no LDS.
// mfma_f32_16x16x32_f16: A lane: row=l&15, k=(l>>4)*8+i; B lane: col=l&15, same k.
// D: col=lane&15, row=(lane>>4)*4+reg  [m89, dtype-independent].
__global__ __launch_bounds__(256) void mfma_matmul_kernel(const _Float16* __restrict__ A,
                                                          const _Float16* __restrict__ Wh,
                                                          float* __restrict__ out, int N) {
    const int wave = threadIdx.x >> 6;
    const int lane = threadIdx.x & 63;
    const int row0 = blockIdx.x * 64 + wave * 16;
    if (row0 >= N) return;
    const int r = lane & 15;
    const int kg = lane >> 4;

    v8hf a[4];
    const int arow = row0 + r;
    if (arow < N) {
        const v8hf* ap = (const v8hf*)(A + (size_t)arow * C + kg * 8);
#pragma unroll
        for (int kk = 0; kk < 4; ++kk) a[kk] = ap[kk * 4];   // +32 fp16 per step
    } else {
#pragma unroll
        for (int kk = 0; kk < 4; ++kk)
#pragma unroll
            for (int q = 0; q < 8; ++q) a[kk][q] = (_Float16)0.0f;
    }

#pragma unroll
    for (int t = 0; t < 8; ++t) {
        v4f acc = {0.0f, 0.0f, 0.0f, 0.0f};
        const v8hf* bp = (const v8hf*)(Wh + (size_t)(t * 16 + r) * C + kg * 8);
#pragma unroll
        for (int kk = 0; kk < 4; ++kk)
            acc = __builtin_amdgcn_mfma_f32_16x16x32_f16(a[kk], bp[kk * 4], acc, 0, 0, 0);
#pragma unroll
        for (int reg = 0; reg < 4; ++reg) {
            int rr = row0 + kg * 4 + reg;
            if (rr < N) out[(size_t)rr * C + t * 16 + r] = acc[reg];
        }
    }
}

extern "C" void kernel_launch(void* const* d_in, const int* in_sizes, int n_in,
                              void* d_out, int out_size, void* d_ws, size_t ws_size,
                              hipStream_t stream) {
    const float* x  = (const float*)d_in[0];
    const int*   ei = (const int*)d_in[1];
    const float* W  = (const float*)d_in[2];
    float* out = (float*)d_out;

    const int N = in_sizes[0] / C;
    const int E = in_sizes[1] / 2;
    const int* rowI = ei;        // edge_index[0]
    const int* colI = ei + E;    // edge_index[1]

    const int NB = (N + BWIDTH - 1) / BWIDTH;     // 196 for N=100000

    // workspace carve-up (256B-aligned regions)
    char* ws = (char*)d_ws;
    size_t off = 0;
    auto carve = [&](size_t bytes) -> void* {
        off = (off + 255) & ~(size_t)255;
        void* p = ws + off;
        off += bytes;
        return p;
    };
    int*      bcount   = (int*)carve((size_t)NBMAX * 4);
    int*      bstart   = (int*)carve((size_t)(NBMAX + 1) * 4);
    int*      gcur     = (int*)carve((size_t)NBMAX * 4);
    int*      offs_end = (int*)carve((size_t)N * 4);
    float*    inv      = (float*)carve((size_t)N * 4);
    int*      csr      = (int*)carve((size_t)E * 4);
    __half2*  xsh      = (__half2*)carve((size_t)N * C * 2);
    // ebuf (dead after p3_place) and aggh (written by gather) share a region
    unsigned* ebuf;
    _Float16* aggh;
    {
        off = (off + 255) & ~(size_t)255;
        ebuf = (unsigned*)(ws + off);
        aggh = (_Float16*)(ws + off);
        size_t esz = (size_t)E * 4, asz = (size_t)N * C * 2;
        off += (esz > asz ? esz : asz);
    }
    __half2*  Wh = (__half2*)carve((size_t)C * C * 2);

    hipMemsetAsync(bcount, 0, (size_t)NBMAX * 4, stream);

    wconv_kernel<<<(C * C / 4 + 255) / 256, 256, 0, stream>>>((const float4*)W, Wh, C * C / 4);

    int E4 = E >> 2;
    bucket_hist_kernel<<<256, 256, 0, stream>>>((const int4*)rowI, rowI, bcount, E4, E, NB);
    bucket_scan_kernel<<<1, 64, 0, stream>>>(bcount, bstart, gcur, NB);

    int nChunks = (E + 4095) / 4096;
    p2_scatter_kernel<<<nChunks, 256, 0, stream>>>(rowI, colI, gcur, ebuf, E);
    p3_place_kernel<<<NB, 512, 0, stream>>>(ebuf, bstart, offs_end, inv, csr, N);

    int total4 = N * (C / 4);
    prescale_kernel<<<(total4 + 255) / 256, 256, 0, stream>>>((const float4*)x, inv, xsh,
                                                              total4);

    long long gt = (long long)N * 16;
    gather_kernel<<<(int)((gt + 255) / 256), 256, 0, stream>>>((const float4*)xsh, offs_end,
                                                               csr, inv, (float4*)aggh, N);

    mfma_matmul_kernel<<<(N + 63) / 64, 256, 0, stream>>>(aggh, (const _Float16*)Wh, out, N);
}